// Round 3
// baseline (85.321 us; speedup 1.0000x reference)
//
#include <hip/hip_runtime.h>

// GNNComm: out[i,:] = mean_{j!=i} relu(concat(m_i,m_j)@W1^T + b1) @ W2^T + b2
// N=2048, D=8, H=64.
//
// relu(z) = (z+|z|)/2 =>
//   S[i,h] = sum_j relu(a_ih + x_jh) = 0.5*(N*a_ih + SX_h + C_ih),
//   C_ih = sum_j |a_ih + x_jh|, a = X1[i]+b1, x = X2[j], SX = sum_j x_jh
// out[i,d] = 0.5*sum_h (C_ih + SX_h + N*a_ih - 2*relu(a_ih+x_ih)) W2[d,h]
//            / (N-1) + b2[d]
//
// R6: R5's grid.sync cooperative launch silently no-oped under the
// harness's graph capture (absmax == max|ref|, out never written) --
// cooperative launch is a graph-capture tripwire. Back to plain
// dispatches: (1) tiny out-zero kernel, (2) ONE fused kernel that
// recomputes its A-frag/X2-chunk in-block from msg/W1 (kills the prep
// dispatch + global round-trip) and uses R3's proven ~free atomicAdd
// epilogue. Geometry change: i-tile 128 x j-chunk 64, 8 i-rows/thread.
// R3's 4-row version was DS-bound (per CU per j-iter: 16 waves x 1
// ds_read_b128 x 12cy = 192cy > 128cy VALU); 8 rows doubles VALU per DS
// read -> VALU-bound main loop (~7us floor vs ~10us).

#define NN 2048
#define HH 64
#define DD 8

#define ITILE 128
#define ITILES (NN / ITILE)    // 16
#define JCHUNK 64
#define JCHUNKS (NN / JCHUNK)  // 32
#define INV_SCALE (0.5f / (float)(NN - 1))

__device__ __forceinline__ float dot8(const float4 m0, const float4 m1,
                                      const float4 w0, const float4 w1) {
    return m0.x * w0.x + m0.y * w0.y + m0.z * w0.z + m0.w * w0.w
         + m1.x * w1.x + m1.y * w1.y + m1.z * w1.z + m1.w * w1.w;
}

// --- K1: zero the atomic target (16 blocks, float4 stores) ---
__global__ void zero_out(float* __restrict__ out) {
    int idx = blockIdx.x * 256 + threadIdx.x;
    ((float4*)out)[idx] = make_float4(0.f, 0.f, 0.f, 0.f);
}

// --- K2: in-block prep + pairwise |a+x| + W2 projection + atomic scatter ---
// Block (it,jc): 128 i x 64 h x 64 j. Thread: hq=tid&15 (4 h's), il=tid>>4 (8 i's).
__global__ void __launch_bounds__(256, 2)
fused(const float* __restrict__ msg,
      const float* __restrict__ W1,
      const float* __restrict__ b1,
      const float* __restrict__ W2,
      const float* __restrict__ b2,
      float* __restrict__ out) {
    __shared__ float  sX2f[JCHUNK * HH];  // [64 j][64 h] = 16KB
    __shared__ float  T[ITILE][68];       // per-block tile, padded = 34.8KB
    __shared__ float4 sSXv[16];           // chunk column-sums of X2

    int it = blockIdx.x & (ITILES - 1);   // 0..15
    int jc = blockIdx.x >> 4;             // 0..31
    int hq = threadIdx.x & 15;
    int il = threadIdx.x >> 4;            // 0..15
    int h0 = hq * 4;
    int i0 = it * ITILE + il * 8;         // 8 consecutive i-rows per thread
    // sub-chunk (global j-chunk index) containing this thread's i-rows:
    int myChunk = it * 2 + (il >> 3);     // uniform per thread
    bool des = (myChunk == jc);           // these 8 rows hit the diagonal here

    const float4* mv = (const float4*)msg;  // [N][2] float4

    // --- phase 1a: A-fragment in registers: a[k][hh] = msg[i0+k].W1[h0+hh][:8] + b1 ---
    float a[8][4];
    {
        float4 mr[8][2];
#pragma unroll
        for (int k = 0; k < 8; ++k) {
            mr[k][0] = mv[(i0 + k) * 2];
            mr[k][1] = mv[(i0 + k) * 2 + 1];
        }
#pragma unroll
        for (int hh = 0; hh < 4; ++hh) {
            const float4* w4 = (const float4*)(W1 + (h0 + hh) * 16);
            float4 wa = w4[0], wb = w4[1];
            float bv = b1[h0 + hh];
#pragma unroll
            for (int k = 0; k < 8; ++k)
                a[k][hh] = dot8(mr[k][0], mr[k][1], wa, wb) + bv;
        }
    }

    // --- phase 1b: X2 chunk into LDS: sX2f[jl][h] = msg[jc*64+jl].W1[h][8:] ---
    {
        int j0 = jc * 64 + il * 4;        // 4 j-rows per thread
        float4 n0a = mv[(j0 + 0) * 2], n0b = mv[(j0 + 0) * 2 + 1];
        float4 n1a = mv[(j0 + 1) * 2], n1b = mv[(j0 + 1) * 2 + 1];
        float4 n2a = mv[(j0 + 2) * 2], n2b = mv[(j0 + 2) * 2 + 1];
        float4 n3a = mv[(j0 + 3) * 2], n3b = mv[(j0 + 3) * 2 + 1];
        float x2v[4][4];
#pragma unroll
        for (int hh = 0; hh < 4; ++hh) {
            const float4* w4 = (const float4*)(W1 + (h0 + hh) * 16);
            float4 wc = w4[2], wd = w4[3];
            x2v[0][hh] = dot8(n0a, n0b, wc, wd);
            x2v[1][hh] = dot8(n1a, n1b, wc, wd);
            x2v[2][hh] = dot8(n2a, n2b, wc, wd);
            x2v[3][hh] = dot8(n3a, n3b, wc, wd);
        }
#pragma unroll
        for (int k = 0; k < 4; ++k)
            *(float4*)&sX2f[(il * 4 + k) * HH + h0] =
                make_float4(x2v[k][0], x2v[k][1], x2v[k][2], x2v[k][3]);
    }

    float acc[8][4];
#pragma unroll
    for (int k = 0; k < 8; ++k)
#pragma unroll
        for (int hh = 0; hh < 4; ++hh)
            acc[k][hh] = 0.f;

    __syncthreads();

    // --- main loop: C[i,h] += |a_ih + x_jh| over the 64-j chunk (VALU-bound) ---
#pragma unroll 2
    for (int j = 0; j < JCHUNK; ++j) {
        float4 x = *(const float4*)&sX2f[j * HH + h0];
#pragma unroll
        for (int k = 0; k < 8; ++k) {
            acc[k][0] += __builtin_fabsf(a[k][0] + x.x);
            acc[k][1] += __builtin_fabsf(a[k][1] + x.y);
            acc[k][2] += __builtin_fabsf(a[k][2] + x.z);
            acc[k][3] += __builtin_fabsf(a[k][3] + x.w);
        }
    }

    // chunk column-sums of X2 (wave-0 tail loop; stall hidden by other waves)
    if (threadIdx.x < 64) {
        float s0 = 0.f, s1 = 0.f, s2 = 0.f, s3 = 0.f;
#pragma unroll 8
        for (int j = 0; j < JCHUNK; j += 4) {
            s0 += sX2f[(j + 0) * 64 + threadIdx.x];
            s1 += sX2f[(j + 1) * 64 + threadIdx.x];
            s2 += sX2f[(j + 2) * 64 + threadIdx.x];
            s3 += sX2f[(j + 3) * 64 + threadIdx.x];
        }
        ((float*)sSXv)[threadIdx.x] = (s0 + s1) + (s2 + s3);
    }

    // write tile to LDS; diagonal rows fold in N*a - 2*relu(a + x_i)
#pragma unroll
    for (int k = 0; k < 8; ++k) {
        float t0 = acc[k][0], t1 = acc[k][1], t2 = acc[k][2], t3 = acc[k][3];
        if (des) {
            int jl = (il & 7) * 8 + k;  // local j index == local i index on diagonal
            float z0 = a[k][0] + sX2f[jl * 64 + h0 + 0];
            float z1 = a[k][1] + sX2f[jl * 64 + h0 + 1];
            float z2 = a[k][2] + sX2f[jl * 64 + h0 + 2];
            float z3 = a[k][3] + sX2f[jl * 64 + h0 + 3];
            t0 += (float)NN * a[k][0] - 2.f * (z0 > 0.f ? z0 : 0.f);
            t1 += (float)NN * a[k][1] - 2.f * (z1 > 0.f ? z1 : 0.f);
            t2 += (float)NN * a[k][2] - 2.f * (z2 > 0.f ? z2 : 0.f);
            t3 += (float)NN * a[k][3] - 2.f * (z3 > 0.f ? z3 : 0.f);
        }
        *(float4*)&T[il * 8 + k][h0] = make_float4(t0, t1, t2, t3);
    }
    __syncthreads();

    // project (T + sSX) onto W2 rows -> atomicAdd into out (R3-proven ~free)
    {
        int iL = threadIdx.x >> 3;        // 0..31; rows iL, iL+32, iL+64, iL+96
        int d  = threadIdx.x & 7;
        const float4* w2v = (const float4*)W2;  // [8][16]
        float s0 = 0.f, s1 = 0.f, s2 = 0.f, s3 = 0.f, c = 0.f;
#pragma unroll
        for (int hb = 0; hb < 16; ++hb) {
            float4 w  = w2v[d * 16 + hb];
            float4 t0 = *(const float4*)&T[iL][hb * 4];
            float4 t1 = *(const float4*)&T[iL + 32][hb * 4];
            float4 t2 = *(const float4*)&T[iL + 64][hb * 4];
            float4 t3 = *(const float4*)&T[iL + 96][hb * 4];
            float4 sx = sSXv[hb];
            s0 += t0.x * w.x + t0.y * w.y + t0.z * w.z + t0.w * w.w;
            s1 += t1.x * w.x + t1.y * w.y + t1.z * w.z + t1.w * w.w;
            s2 += t2.x * w.x + t2.y * w.y + t2.z * w.z + t2.w * w.w;
            s3 += t3.x * w.x + t3.y * w.y + t3.z * w.z + t3.w * w.w;
            c  += sx.x * w.x + sx.y * w.y + sx.z * w.z + sx.w * w.w;
        }
        float v0 = (s0 + c) * INV_SCALE;
        float v1 = (s1 + c) * INV_SCALE;
        float v2 = (s2 + c) * INV_SCALE;
        float v3 = (s3 + c) * INV_SCALE;
        // b2 added once per i-row: by the block whose jc covers that row.
        // row iL+32q lives in global chunk it*2 + (q>>1).
        float bv = b2[d];
        if (jc == it * 2)     { v0 += bv; v1 += bv; }
        if (jc == it * 2 + 1) { v2 += bv; v3 += bv; }
        int ibase = it * ITILE;
        atomicAdd(&out[(ibase + iL) * DD + d],      v0);
        atomicAdd(&out[(ibase + iL + 32) * DD + d], v1);
        atomicAdd(&out[(ibase + iL + 64) * DD + d], v2);
        atomicAdd(&out[(ibase + iL + 96) * DD + d], v3);
    }
}

extern "C" void kernel_launch(void* const* d_in, const int* in_sizes, int n_in,
                              void* d_out, int out_size, void* d_ws, size_t ws_size,
                              hipStream_t stream) {
    const float* msg = (const float*)d_in[0];  // [N, 8]
    const float* W1  = (const float*)d_in[1];  // [64, 16]
    const float* b1  = (const float*)d_in[2];  // [64]
    const float* W2  = (const float*)d_in[3];  // [8, 64]
    const float* b2  = (const float*)d_in[4];  // [8]
    float* out = (float*)d_out;                // [N, 8]

    zero_out<<<(NN * DD) / (256 * 4), 256, 0, stream>>>(out);
    fused<<<ITILES * JCHUNKS, 256, 0, stream>>>(msg, W1, b1, W2, b2, out);
}